// Round 7
// baseline (1673.499 us; speedup 1.0000x reference)
//
#include <hip/hip_runtime.h>
#include <math.h>

// GraphGPS GatedGCN stack, fused single cooperative kernel. R7:
// = R6 structure (TPB 1024, swizzled eT, stride-84 node bufs, packed CSR)
// + amdgpu_waves_per_eu(4,4): pins exactly 4 waves/EU (one 16-wave block/CU,
//   which dynamic-LDS already enforces) so the allocator gets the full
//   128-VGPR budget. R5/R6 allocator chose 64 VGPR + ~200MB scratch spill
//   traffic per dispatch (FETCH+WRITE ~99+98 MB) targeting phantom 2-block
//   occupancy.

#define TPB 1024
#define NBLK 256
#define DD 70
#define ETS 256      // eT row stride
#define NBS 84       // node-buffer row stride (20 mod 32)
#define SLS 80       // W slab k-stride
#define NLAYERS 17
#define SPL 280
#define NSLOT 8
#define EPS_AGG 1e-6f
#define EPS_BN 1e-5f
#define EPS_LN 1e-5f

#define SCX 0
#define SHX 72
#define SCE 144
#define SHE 216
#define SBO 288
#define BAO 360
#define BBO 432
#define ZBO 504
#define STATL_F 576

#define OFF_ET   0
#define OFF_HN   (OFF_ET + 72*ETS)            // 18432
#define OFF_AX   (OFF_HN + 32*NBS)
#define OFF_BX   (OFF_AX + 32*NBS)
#define OFF_DX   (OFF_BX + 32*NBS)
#define OFF_EX   (OFF_DX + 32*NBS)
#define OFF_SLAB (OFF_EX + 32*NBS)
#define OFF_STATL (OFF_SLAB + 72*SLS)
#define SMEM_FLOATS (OFF_STATL + STATL_F)     // 38208
#define SMEM_BYTES  (SMEM_FLOATS*4 + (32+33)*4 + 512 + 512 + 16)

// swizzled eT index: row k, edge e
#define EIX(k,e) (((k)<<8) + ((e) ^ ((((k)>>2)&7)<<2)))

struct GPSParams {
  const float* __restrict__ x; const int* __restrict__ ei; const float* __restrict__ ea;
  const float* __restrict__ wn; const float* __restrict__ bnn;
  const float* __restrict__ we; const float* __restrict__ web;
  const float* __restrict__ Aw[2]; const float* __restrict__ Ab[2];
  const float* __restrict__ Bw[2]; const float* __restrict__ Bb[2];
  const float* __restrict__ Cw[2]; const float* __restrict__ Cb[2];
  const float* __restrict__ Dw[2]; const float* __restrict__ Db[2];
  const float* __restrict__ Ew[2]; const float* __restrict__ Eb[2];
  const float* __restrict__ gx[2]; const float* __restrict__ bx[2];
  const float* __restrict__ ge[2]; const float* __restrict__ gbe[2];
  const float* __restrict__ c1w; const float* __restrict__ c1b;
  const float* __restrict__ lng; const float* __restrict__ lnb;
  const float* __restrict__ c2w; const float* __restrict__ c2b;
  float* __restrict__ out; float* __restrict__ stats; unsigned* __restrict__ bar;
};

__device__ __forceinline__ void grid_sync(unsigned* b) {
  __syncthreads();
  if (threadIdx.x == 0) {
    unsigned g = __hip_atomic_load(b, __ATOMIC_RELAXED, __HIP_MEMORY_SCOPE_AGENT);
    int leaf = (int)(blockIdx.x >> 4);
    unsigned a = __hip_atomic_fetch_add(b + 32 + leaf*32, 1u, __ATOMIC_ACQ_REL, __HIP_MEMORY_SCOPE_AGENT);
    bool done = false;
    if (a == 15u) {
      unsigned r = __hip_atomic_fetch_add(b + 16, 1u, __ATOMIC_ACQ_REL, __HIP_MEMORY_SCOPE_AGENT);
      if (r == 15u) {
        #pragma unroll
        for (int i2 = 0; i2 < 16; ++i2)
          __hip_atomic_store(b + 32 + i2*32, 0u, __ATOMIC_RELAXED, __HIP_MEMORY_SCOPE_AGENT);
        __hip_atomic_store(b + 16, 0u, __ATOMIC_RELAXED, __HIP_MEMORY_SCOPE_AGENT);
        __hip_atomic_store(b, g + 1u, __ATOMIC_RELEASE, __HIP_MEMORY_SCOPE_AGENT);
        done = true;
      }
    }
    if (!done) {
      while (__hip_atomic_load(b, __ATOMIC_ACQUIRE, __HIP_MEMORY_SCOPE_AGENT) == g)
        __builtin_amdgcn_s_sleep(2);
    }
  }
  __syncthreads();
}

// stage W (70x70 row-major [k][j]) -> slab transposed [72][80], pads zero
__device__ __forceinline__ void stage_wt(float* __restrict__ slab,
                                         const float* __restrict__ W, int tid) {
  for (int i = tid; i < 72*SLS; i += TPB) {
    int j = i / SLS, K = i % SLS;
    slab[i] = (j < DD && K < DD) ? W[K*DD + j] : 0.f;
  }
}

__global__ void __launch_bounds__(TPB)
__attribute__((amdgpu_waves_per_eu(4, 4)))
gps_kernel(GPSParams p) {
  extern __shared__ float smem[];
  float* eT    = smem + OFF_ET;      // [72][256], swizzled, rows 70/71 zero
  float* hN    = smem + OFF_HN;      // [32][84], cols 70..83 zero
  float* Ax    = smem + OFF_AX;
  float* Bx    = smem + OFF_BX;
  float* Dx    = smem + OFF_DX;
  float* Ex    = smem + OFF_EX;
  float* slab  = smem + OFF_SLAB;    // [72][80]
  float* statl = smem + OFF_STATL;
  int*   icur  = (int*)(smem + SMEM_FLOATS);
  int*   ioff  = icur + 32;
  unsigned char* srcloc = (unsigned char*)(ioff + 33);
  unsigned char* dstloc = srcloc + 256;
  unsigned short* eidxS = (unsigned short*)(dstloc + 256);

  const int tid  = threadIdx.x;
  const int g    = blockIdx.x;
  const int lane = tid & 63;

  // edge roles: thread -> (cg, epi); 2 edges per thread
  const int cg  = (tid >> 6) & 7;
  const int jbe = cg * 9;
  const int epi = ((tid >> 9) << 6) | lane;
  const int e0  = epi * 2;
  // node roles: thread -> (cg, n, kq); kq in lane bits 4-5 for shfl combine
  const int n_n  = ((tid >> 9) << 4) | (tid & 15);
  const int n_kq = (tid >> 4) & 3;
  const int n_k0 = n_kq * 20;
  // BN-apply roles: 32 j-lanes x 32 nodes
  const int a_n = tid >> 5, a_j = tid & 31;

  float* slot = p.stats + ((g >> 5) * NLAYERS) * SPL;

  // ---------------- CSR build ----------------
  if (tid < 32) icur[tid] = 0;
  __syncthreads();
  if (tid < 256) {
    int s0 = p.ei[g*256 + tid]         - g*32;
    int d0 = p.ei[65536 + g*256 + tid] - g*32;
    srcloc[tid] = (unsigned char)s0;
    dstloc[tid] = (unsigned char)d0;
    atomicAdd(&icur[d0], 1);
  }
  __syncthreads();
  if (tid == 0) {
    int o = 0;
    for (int n = 0; n < 32; ++n) { ioff[n] = o; o += icur[n]; }
    ioff[32] = o;
  }
  __syncthreads();
  if (tid < 32) icur[tid] = ioff[tid];
  __syncthreads();
  if (tid < 256) {
    int d0 = dstloc[tid];
    int sl2 = atomicAdd(&icur[d0], 1);
    eidxS[sl2] = (unsigned short)(tid | ((int)srcloc[tid] << 8));
  }

  // ---------------- init ----------------
  for (int i = tid; i < 5*32*NBS; i += TPB) hN[i] = 0.f;   // hN..Ex contiguous
  for (int i = tid; i < STATL_F; i += TPB) statl[i] = 0.f;
  for (int i = tid; i < 2*ETS; i += TPB) eT[70*ETS + i] = 0.f;  // pad rows
  __syncthreads();
  for (int i = tid; i < 32*DD; i += TPB) {
    int n = i / DD, j = i % DD;
    hN[n*NBS + j] = fmaf(p.x[g*32 + n], p.wn[j], p.bnn[j]);
  }
  for (int i = tid; i < DD*256; i += TPB) {
    int k = i >> 8, e = i & 255;
    eT[EIX(k, e)] = fmaf(p.ea[g*256 + e], p.we[k], p.web[k]);
  }
  __syncthreads();

  auto node_phase = [&](const float* __restrict__ W, float* __restrict__ nbuf, int boff) {
    stage_wt(slab, W, tid);
    __syncthreads();
    float acc[9];
    #pragma unroll
    for (int i = 0; i < 9; ++i) acc[i] = 0.f;
    const float* hrow = hN + n_n*NBS + n_k0;
    #pragma unroll
    for (int c = 0; c < 5; ++c) {
      float4 h4 = *(const float4*)(hrow + c*4);
      #pragma unroll
      for (int i = 0; i < 9; ++i) {
        const float* wr = slab + (jbe + i)*SLS + n_k0 + c*4;
        float4 w4 = *(const float4*)wr;
        acc[i] = fmaf(h4.x, w4.x, acc[i]);
        acc[i] = fmaf(h4.y, w4.y, acc[i]);
        acc[i] = fmaf(h4.z, w4.z, acc[i]);
        acc[i] = fmaf(h4.w, w4.w, acc[i]);
      }
    }
    #pragma unroll
    for (int i = 0; i < 9; ++i) {
      acc[i] += __shfl_xor(acc[i], 16, 64);
      acc[i] += __shfl_xor(acc[i], 32, 64);
    }
    if (n_kq == 0) {
      #pragma unroll
      for (int i = 0; i < 9; ++i) {
        int j = jbe + i;
        if (j < DD) nbuf[n_n*NBS + j] = acc[i] + statl[boff + j];
      }
    }
    __syncthreads();
  };

  // ---------------- layer loop ----------------
  #pragma unroll 1
  for (int L = 0; L < NLAYERS; ++L) {
    const int s = (L == 0) ? 0 : 1;
    float* lslot = slot + L * SPL;

    if (tid < DD) {
      statl[BAO + tid] = p.Ab[s][tid];
      statl[BBO + tid] = p.Bb[s][tid];
      statl[SBO + tid] = p.Cb[s][tid] + p.Db[s][tid] + p.Eb[s][tid];
    }
    node_phase(p.Aw[s], Ax, BAO);
    node_phase(p.Bw[s], Bx, BBO);
    node_phase(p.Dw[s], Dx, ZBO);
    node_phase(p.Ew[s], Ex, ZBO);

    stage_wt(slab, p.Cw[s], tid);
    __syncthreads();

    // ---- edge GEMM: acc[r][i] = sum_k e[e0+r][k] * Cw[k][jbe+i]
    float acc[2][9];
    #pragma unroll
    for (int r = 0; r < 2; ++r)
      #pragma unroll
      for (int i = 0; i < 9; ++i) acc[r][i] = 0.f;

    #pragma unroll 1
    for (int c = 0; c < 9; ++c) {
      const int K0 = c*8;
      float2 ev[8];
      #pragma unroll
      for (int kk = 0; kk < 8; ++kk)
        ev[kk] = *(const float2*)(eT + EIX(K0 + kk, e0));
      #pragma unroll
      for (int i = 0; i < 9; ++i) {
        const float* wr = slab + (jbe + i)*SLS + K0;
        float4 w03 = *(const float4*)(wr);
        float4 w47 = *(const float4*)(wr + 4);
        acc[0][i] = fmaf(ev[0].x, w03.x, acc[0][i]); acc[1][i] = fmaf(ev[0].y, w03.x, acc[1][i]);
        acc[0][i] = fmaf(ev[1].x, w03.y, acc[0][i]); acc[1][i] = fmaf(ev[1].y, w03.y, acc[1][i]);
        acc[0][i] = fmaf(ev[2].x, w03.z, acc[0][i]); acc[1][i] = fmaf(ev[2].y, w03.z, acc[1][i]);
        acc[0][i] = fmaf(ev[3].x, w03.w, acc[0][i]); acc[1][i] = fmaf(ev[3].y, w03.w, acc[1][i]);
        acc[0][i] = fmaf(ev[4].x, w47.x, acc[0][i]); acc[1][i] = fmaf(ev[4].y, w47.x, acc[1][i]);
        acc[0][i] = fmaf(ev[5].x, w47.y, acc[0][i]); acc[1][i] = fmaf(ev[5].y, w47.y, acc[1][i]);
        acc[0][i] = fmaf(ev[6].x, w47.z, acc[0][i]); acc[1][i] = fmaf(ev[6].y, w47.z, acc[1][i]);
        acc[0][i] = fmaf(ev[7].x, w47.w, acc[0][i]); acc[1][i] = fmaf(ev[7].y, w47.w, acc[1][i]);
      }
    }

    // eold (residual base)
    float2 eo[9];
    #pragma unroll
    for (int i = 0; i < 9; ++i) {
      int j = jbe + i;
      if (j < DD) eo[i] = *(const float2*)(eT + EIX(j, e0));
      else { eo[i].x = 0.f; eo[i].y = 0.f; }
    }
    // += Dx[dst] + Ex[src] + (Cb+Db+Eb)
    {
      int d0 = dstloc[e0],   s0 = srcloc[e0];
      int d1 = dstloc[e0+1], s1 = srcloc[e0+1];
      const float* dx0 = Dx + d0*NBS; const float* ex0 = Ex + s0*NBS;
      const float* dx1 = Dx + d1*NBS; const float* ex1 = Ex + s1*NBS;
      #pragma unroll
      for (int i = 0; i < 9; ++i) {
        int j = jbe + i;
        if (j < DD) {
          float bb = statl[SBO + j];
          acc[0][i] += dx0[j] + ex0[j] + bb;
          acc[1][i] += dx1[j] + ex1[j] + bb;
        }
      }
    }

    // e-stats from registers (wave covers 128 edges for its 9 cols)
    #pragma unroll
    for (int i = 0; i < 9; ++i) {
      int j = jbe + i;
      float ps = acc[0][i] + acc[1][i];
      float qs = fmaf(acc[0][i], acc[0][i], acc[1][i]*acc[1][i]);
      #pragma unroll
      for (int d = 1; d < 64; d <<= 1) {
        ps += __shfl_xor(ps, d, 64);
        qs += __shfl_xor(qs, d, 64);
      }
      if (lane == 0 && j < DD) {
        atomicAdd(lslot + 140 + j, ps);
        atomicAdd(lslot + 210 + j, qs);
      }
    }
    __syncthreads();   // all eT reads complete

    // sigmoid in place into eT
    #pragma unroll
    for (int i = 0; i < 9; ++i) {
      int j = jbe + i;
      if (j < DD) {
        float2 sg;
        sg.x = 1.f / (1.f + __expf(-acc[0][i]));
        sg.y = 1.f / (1.f + __expf(-acc[1][i]));
        *(float2*)(eT + EIX(j, e0)) = sg;
      }
    }
    __syncthreads();

    // gather: x_new = Ax + num/den (RMW into Ax). item=(n,jq), sub splits edges.
    {
      auto gath = [&](int item, int sub) {
        int n = item / 18, jq = item % 18;
        int j0 = jq * 4;
        bool v2 = (j0 + 2) < DD, v3 = (j0 + 3) < DD;
        float nm0 = 0.f, nm1 = 0.f, nm2 = 0.f, nm3 = 0.f;
        float dn0 = 0.f, dn1 = 0.f, dn2 = 0.f, dn3 = 0.f;
        int pb = ioff[n], pe = ioff[n + 1];
        int mid = (pb + pe + 1) >> 1;
        int lo = sub ? mid : pb;
        int hi = sub ? pe : mid;
        for (int pp = lo; pp < hi; ++pp) {
          unsigned v = eidxS[pp];
          int e2 = v & 255, sl2 = v >> 8;
          float s0 = eT[EIX(j0 + 0, e2)];
          float s1 = eT[EIX(j0 + 1, e2)];
          float s2 = v2 ? eT[EIX(j0 + 2, e2)] : 0.f;
          float s3 = v3 ? eT[EIX(j0 + 3, e2)] : 0.f;
          float4 b4 = *(const float4*)(Bx + sl2*NBS + j0);
          nm0 = fmaf(s0, b4.x, nm0); nm1 = fmaf(s1, b4.y, nm1);
          nm2 = fmaf(s2, b4.z, nm2); nm3 = fmaf(s3, b4.w, nm3);
          dn0 += s0; dn1 += s1; dn2 += s2; dn3 += s3;
        }
        // combine the two edge-halves (lanes tid, tid^1)
        nm0 += __shfl_xor(nm0, 1, 64); dn0 += __shfl_xor(dn0, 1, 64);
        nm1 += __shfl_xor(nm1, 1, 64); dn1 += __shfl_xor(dn1, 1, 64);
        nm2 += __shfl_xor(nm2, 1, 64); dn2 += __shfl_xor(dn2, 1, 64);
        nm3 += __shfl_xor(nm3, 1, 64); dn3 += __shfl_xor(dn3, 1, 64);
        if (sub == 0) {
          float* axp = Ax + n*NBS + j0;
          float4 ax = *(const float4*)axp;
          ax.x += nm0 / (dn0 + EPS_AGG);
          ax.y += nm1 / (dn1 + EPS_AGG);
          ax.z += nm2 / (dn2 + EPS_AGG);
          ax.w += nm3 / (dn3 + EPS_AGG);
          *(float4*)axp = ax;
        }
      };
      gath(tid >> 1, tid & 1);               // items 0..511
      if (tid < 128) gath(512 + (tid >> 1), tid & 1);  // items 512..575
    }
    __syncthreads();

    // x-stats (280 threads: 70 cols x 4 node-quarters)
    if (tid < SPL) {
      int col = tid % DD, q = tid / DD;
      float sm = 0.f, sq = 0.f;
      #pragma unroll
      for (int r = 0; r < 8; ++r) {
        float v = Ax[(q*8 + r)*NBS + col];
        sm += v; sq = fmaf(v, v, sq);
      }
      atomicAdd(lslot + col, sm);
      atomicAdd(lslot + 70 + col, sq);
    }

    grid_sync(p.bar);

    // BN scale/shift from 8 slots
    if (tid < DD) {
      float sm = 0.f, sq = 0.f;
      #pragma unroll
      for (int sl2 = 0; sl2 < NSLOT; ++sl2) {
        const float* st = p.stats + (sl2*NLAYERS + L)*SPL;
        sm += __hip_atomic_load(st + tid,      __ATOMIC_RELAXED, __HIP_MEMORY_SCOPE_AGENT);
        sq += __hip_atomic_load(st + 70 + tid, __ATOMIC_RELAXED, __HIP_MEMORY_SCOPE_AGENT);
      }
      float mean = sm * (1.f/8192.f);
      float var  = sq * (1.f/8192.f) - mean*mean;
      float sc = p.gx[s][tid] * rsqrtf(var + EPS_BN);
      statl[SCX + tid] = sc;
      statl[SHX + tid] = fmaf(-mean, sc, p.bx[s][tid]);
    } else if (tid < 140) {
      int j = tid - DD;
      float sm = 0.f, sq = 0.f;
      #pragma unroll
      for (int sl2 = 0; sl2 < NSLOT; ++sl2) {
        const float* st = p.stats + (sl2*NLAYERS + L)*SPL;
        sm += __hip_atomic_load(st + 140 + j, __ATOMIC_RELAXED, __HIP_MEMORY_SCOPE_AGENT);
        sq += __hip_atomic_load(st + 210 + j, __ATOMIC_RELAXED, __HIP_MEMORY_SCOPE_AGENT);
      }
      float mean = sm * (1.f/65536.f);
      float var  = sq * (1.f/65536.f) - mean*mean;
      float sc = p.ge[s][j] * rsqrtf(var + EPS_BN);
      statl[SCE + j] = sc;
      statl[SHE + j] = fmaf(-mean, sc, p.gbe[s][j]);
    }
    __syncthreads();

    // apply BN+ReLU+residual: h  (32 nodes x 32 j-lanes, shift-based roles)
    #pragma unroll
    for (int r = 0; r < 3; ++r) {
      int j = a_j + (r << 5);
      if (j < DD) {
        float xn = Ax[a_n*NBS + j];
        hN[a_n*NBS + j] += fmaxf(fmaf(xn, statl[SCX + j], statl[SHX + j]), 0.f);
      }
    }
    // apply BN+ReLU+residual: e (registers -> eT)
    #pragma unroll
    for (int i = 0; i < 9; ++i) {
      int j = jbe + i;
      if (j < DD) {
        float sc = statl[SCE + j], sh = statl[SHE + j];
        float2 r;
        r.x = eo[i].x + fmaxf(fmaf(acc[0][i], sc, sh), 0.f);
        r.y = eo[i].y + fmaxf(fmaf(acc[1][i], sc, sh), 0.f);
        *(float2*)(eT + EIX(j, e0)) = r;
      }
    }
    __syncthreads();
  }

  // ---------------- readout ----------------
  if (tid < DD) {
    float mx = -3.4e38f, sm = 0.f;
    #pragma unroll 4
    for (int r = 0; r < 32; ++r) {
      float v = hN[r*NBS + tid];
      mx = fmaxf(mx, v); sm += v;
    }
    statl[tid]      = mx;               // gmp
    statl[70 + tid] = sm * (1.f/32.f);  // gap
  }
  __syncthreads();
  if (tid < 256) {
    float a = p.c1b[tid];
    for (int k = 0; k < DD; ++k) a = fmaf(statl[k],      p.c1w[k*256 + tid], a);
    for (int k = 0; k < DD; ++k) a = fmaf(statl[70 + k], p.c1w[(DD + k)*256 + tid], a);
    Ax[tid] = fmaxf(a, 0.f);
  }
  __syncthreads();
  if (tid == 0) {
    float sm = 0.f, sq = 0.f;
    for (int k = 0; k < 256; ++k) { float v = Ax[k]; sm += v; sq = fmaf(v, v, sq); }
    float mean = sm * (1.f/256.f);
    float var  = sq * (1.f/256.f) - mean*mean;
    statl[560] = mean;
    statl[561] = rsqrtf(var + EPS_LN);
  }
  __syncthreads();
  if (tid < 256) {
    float v = (Ax[tid] - statl[560]) * statl[561];
    Bx[tid] = fmaf(v, p.lng[tid], p.lnb[tid]);
  }
  __syncthreads();
  if (tid < 10) {
    float a = p.c2b[tid];
    for (int k = 0; k < 256; ++k) a = fmaf(Bx[k], p.c2w[k*10 + tid], a);
    p.out[g*10 + tid] = a;
  }
}

extern "C" void kernel_launch(void* const* d_in, const int* in_sizes, int n_in,
                              void* d_out, int out_size, void* d_ws, size_t ws_size,
                              hipStream_t stream) {
  (void)in_sizes; (void)n_in; (void)out_size; (void)ws_size;
  GPSParams p;
  p.x   = (const float*)d_in[0];
  p.ei  = (const int*)  d_in[1];
  p.ea  = (const float*)d_in[2];
  p.wn  = (const float*)d_in[4];  p.bnn = (const float*)d_in[5];
  p.we  = (const float*)d_in[6];  p.web = (const float*)d_in[7];
  int i = 8;
  for (int s = 0; s < 2; ++s) {
    p.Aw[s] = (const float*)d_in[i++]; p.Ab[s] = (const float*)d_in[i++];
    p.Bw[s] = (const float*)d_in[i++]; p.Bb[s] = (const float*)d_in[i++];
    p.Cw[s] = (const float*)d_in[i++]; p.Cb[s] = (const float*)d_in[i++];
    p.Dw[s] = (const float*)d_in[i++]; p.Db[s] = (const float*)d_in[i++];
    p.Ew[s] = (const float*)d_in[i++]; p.Eb[s] = (const float*)d_in[i++];
    p.gx[s] = (const float*)d_in[i++]; p.bx[s] = (const float*)d_in[i++];
    p.ge[s] = (const float*)d_in[i++]; p.gbe[s] = (const float*)d_in[i++];
  }
  p.c1w = (const float*)d_in[36]; p.c1b = (const float*)d_in[37];
  p.lng = (const float*)d_in[38]; p.lnb = (const float*)d_in[39];
  p.c2w = (const float*)d_in[40]; p.c2b = (const float*)d_in[41];
  p.out = (float*)d_out;
  p.bar = (unsigned*)d_ws;
  p.stats = (float*)((char*)d_ws + 4096);

  hipMemsetAsync(d_ws, 0, 4096 + NSLOT*NLAYERS*SPL*4, stream);

  hipFuncSetAttribute((const void*)gps_kernel,
                      hipFuncAttributeMaxDynamicSharedMemorySize, SMEM_BYTES);

  void* args[] = { (void*)&p };
  hipError_t err = hipLaunchCooperativeKernel((const void*)gps_kernel,
                                              dim3(NBLK), dim3(TPB),
                                              args, SMEM_BYTES, stream);
  if (err != hipSuccess) {
    gps_kernel<<<dim3(NBLK), dim3(TPB), SMEM_BYTES, stream>>>(p);
  }
}

// Round 8
// 1063.034 us; speedup vs baseline: 1.5743x; 1.5743x over previous
//
#include <hip/hip_runtime.h>
#include <hip/hip_fp16.h>
#include <math.h>

// GraphGPS GatedGCN stack, fused single cooperative kernel. R8:
// - TPB 768 (12 waves). Edge: 4 edges x 6 cols/thread (acc[4][6], b128 ev).
//   Node: 6 cols x k-half/thread (1 shfl combine). All threads active.
// - eT[72][256] (swizzled) holds e_OLD all layer; sigmoid goes to a 35KB
//   fp16 side buffer overlaid on Dx+Ex+slab (dead by then). Post-barrier
//   e-residual re-reads e_old from eT -> nothing fat lives across gather
//   -> fits a 64-VGPR budget with no spill (R5-R7 spilled ~200MB/dispatch).
// - sigma layout [j][128 dword cols], col swizzle c^(j&30): b64 writes
//   conflict-free, gather reads ~2-3 way.
// - stats slot = g&7 (XCD affinity), 8 slots, hierarchical grid barrier.

#define TPB 768
#define NBLK 256
#define DD 70
#define ETS 256      // eT row stride (dwords)
#define NBS 84       // node-buffer row stride
#define SLS 80       // W slab k-stride
#define NLAYERS 17
#define SPL 280
#define NSLOT 8
#define EPS_AGG 1e-6f
#define EPS_BN 1e-5f
#define EPS_LN 1e-5f

#define SCX 0
#define SHX 72
#define SCE 144
#define SHE 216
#define SBO 288
#define BAO 360
#define BBO 432
#define ZBO 504
#define STATL_F 576

#define OFF_ET   0
#define OFF_HN   (OFF_ET + 72*ETS)            // 18432
#define OFF_AX   (OFF_HN + 32*NBS)
#define OFF_BX   (OFF_AX + 32*NBS)
#define OFF_DX   (OFF_BX + 32*NBS)            // sigma buffer starts here
#define OFF_EX   (OFF_DX + 32*NBS)
#define OFF_SLAB (OFF_EX + 32*NBS)
#define OFF_STATL (OFF_SLAB + 72*SLS)
#define SMEM_FLOATS (OFF_STATL + STATL_F)     // 38208
#define SMEM_BYTES  (SMEM_FLOATS*4 + (32+33)*4 + 512 + 512 + 16)

// swizzled eT index (dwords): row k, edge e; permutes 16B blocks -> b128-safe
#define EIX(k,e) (((k)<<8) + ((e) ^ ((((k)>>2)&7)<<2)))
// sigma dword index: feature j, dword-col c (= e/2)
#define SIX(j,c) (((j)<<7) + ((c) ^ ((j)&30)))

struct GPSParams {
  const float* __restrict__ x; const int* __restrict__ ei; const float* __restrict__ ea;
  const float* __restrict__ wn; const float* __restrict__ bnn;
  const float* __restrict__ we; const float* __restrict__ web;
  const float* __restrict__ Aw[2]; const float* __restrict__ Ab[2];
  const float* __restrict__ Bw[2]; const float* __restrict__ Bb[2];
  const float* __restrict__ Cw[2]; const float* __restrict__ Cb[2];
  const float* __restrict__ Dw[2]; const float* __restrict__ Db[2];
  const float* __restrict__ Ew[2]; const float* __restrict__ Eb[2];
  const float* __restrict__ gx[2]; const float* __restrict__ bx[2];
  const float* __restrict__ ge[2]; const float* __restrict__ gbe[2];
  const float* __restrict__ c1w; const float* __restrict__ c1b;
  const float* __restrict__ lng; const float* __restrict__ lnb;
  const float* __restrict__ c2w; const float* __restrict__ c2b;
  float* __restrict__ out; float* __restrict__ stats; unsigned* __restrict__ bar;
};

__device__ __forceinline__ void grid_sync(unsigned* b) {
  __syncthreads();
  if (threadIdx.x == 0) {
    unsigned g = __hip_atomic_load(b, __ATOMIC_RELAXED, __HIP_MEMORY_SCOPE_AGENT);
    int leaf = (int)(blockIdx.x >> 4);
    unsigned a = __hip_atomic_fetch_add(b + 32 + leaf*32, 1u, __ATOMIC_ACQ_REL, __HIP_MEMORY_SCOPE_AGENT);
    bool done = false;
    if (a == 15u) {
      unsigned r = __hip_atomic_fetch_add(b + 16, 1u, __ATOMIC_ACQ_REL, __HIP_MEMORY_SCOPE_AGENT);
      if (r == 15u) {
        #pragma unroll
        for (int i2 = 0; i2 < 16; ++i2)
          __hip_atomic_store(b + 32 + i2*32, 0u, __ATOMIC_RELAXED, __HIP_MEMORY_SCOPE_AGENT);
        __hip_atomic_store(b + 16, 0u, __ATOMIC_RELAXED, __HIP_MEMORY_SCOPE_AGENT);
        __hip_atomic_store(b, g + 1u, __ATOMIC_RELEASE, __HIP_MEMORY_SCOPE_AGENT);
        done = true;
      }
    }
    if (!done) {
      while (__hip_atomic_load(b, __ATOMIC_ACQUIRE, __HIP_MEMORY_SCOPE_AGENT) == g)
        __builtin_amdgcn_s_sleep(2);
    }
  }
  __syncthreads();
}

// stage W (70x70 row-major [k][j]) -> slab transposed [72][80], pads zero
__device__ __forceinline__ void stage_wt(float* __restrict__ slab,
                                         const float* __restrict__ W, int tid) {
  for (int i = tid; i < 72*SLS; i += TPB) {
    int j = i / SLS, K = i % SLS;
    slab[i] = (j < DD && K < DD) ? W[K*DD + j] : 0.f;
  }
}

__global__ void __launch_bounds__(TPB)
__attribute__((amdgpu_waves_per_eu(3, 3)))
gps_kernel(GPSParams p) {
  extern __shared__ float smem[];
  float* eT    = smem + OFF_ET;      // [72][256] e_old, swizzled; rows 70/71 = 0
  float* hN    = smem + OFF_HN;      // [32][84], cols >=70 zero
  float* Ax    = smem + OFF_AX;
  float* Bx    = smem + OFF_BX;
  float* Dx    = smem + OFF_DX;
  float* Ex    = smem + OFF_EX;
  float* slab  = smem + OFF_SLAB;    // [72][80]
  float* statl = smem + OFF_STATL;
  unsigned* sigb = (unsigned*)(smem + OFF_DX);   // sigma fp16: 70*128 dwords
  const __half* sigh = (const __half*)sigb;
  int*   icur  = (int*)(smem + SMEM_FLOATS);
  int*   ioff  = icur + 32;
  unsigned char* srcloc = (unsigned char*)(ioff + 33);
  unsigned char* dstloc = srcloc + 256;
  unsigned short* eidxS = (unsigned short*)(dstloc + 256);

  const int tid  = threadIdx.x;
  const int g    = blockIdx.x;
  const int lane = tid & 63;
  const int wid  = tid >> 6;          // 0..11 (wave id)

  // edge roles: wave = col group (6 cols), lane = 4-edge block
  const int jbe = wid * 6;
  const int e0  = lane * 4;
  // node roles: wave = col group, lane -> (kh, n)
  const int n_kh = lane >> 5;
  const int n_n  = lane & 31;
  const int n_k0 = n_kh * 40;

  float* slot = p.stats + ((g & 7) * NLAYERS) * SPL;

  // ---------------- CSR build ----------------
  if (tid < 32) icur[tid] = 0;
  __syncthreads();
  if (tid < 256) {
    int s0 = p.ei[g*256 + tid]         - g*32;
    int d0 = p.ei[65536 + g*256 + tid] - g*32;
    srcloc[tid] = (unsigned char)s0;
    dstloc[tid] = (unsigned char)d0;
    atomicAdd(&icur[d0], 1);
  }
  __syncthreads();
  if (tid == 0) {
    int o = 0;
    for (int n = 0; n < 32; ++n) { ioff[n] = o; o += icur[n]; }
    ioff[32] = o;
  }
  __syncthreads();
  if (tid < 32) icur[tid] = ioff[tid];
  __syncthreads();
  if (tid < 256) {
    int d0 = dstloc[tid];
    int sl2 = atomicAdd(&icur[d0], 1);
    eidxS[sl2] = (unsigned short)(tid | ((int)srcloc[tid] << 8));
  }

  // ---------------- init ----------------
  for (int i = tid; i < 5*32*NBS; i += TPB) hN[i] = 0.f;    // hN..Ex
  for (int i = tid; i < STATL_F; i += TPB) statl[i] = 0.f;
  for (int i = tid; i < 2*ETS; i += TPB) eT[70*ETS + i] = 0.f;  // pad rows
  __syncthreads();
  for (int i = tid; i < 32*DD; i += TPB) {
    int n = i / DD, j = i % DD;
    hN[n*NBS + j] = fmaf(p.x[g*32 + n], p.wn[j], p.bnn[j]);
  }
  for (int i = tid; i < DD*256; i += TPB) {
    int k = i >> 8, e = i & 255;
    eT[EIX(k, e)] = fmaf(p.ea[g*256 + e], p.we[k], p.web[k]);
  }
  __syncthreads();

  auto node_phase = [&](const float* __restrict__ W, float* __restrict__ nbuf, int boff) {
    stage_wt(slab, W, tid);
    __syncthreads();
    float acc[6];
    #pragma unroll
    for (int i = 0; i < 6; ++i) acc[i] = 0.f;
    const float* hrow = hN + n_n*NBS + n_k0;
    #pragma unroll
    for (int c = 0; c < 5; ++c) {
      float4 ha = *(const float4*)(hrow + c*8);
      float4 hb = *(const float4*)(hrow + c*8 + 4);
      #pragma unroll
      for (int i = 0; i < 6; ++i) {
        const float* wr = slab + (jbe + i)*SLS + n_k0 + c*8;
        float4 wa = *(const float4*)(wr);
        float4 wb = *(const float4*)(wr + 4);
        acc[i] = fmaf(ha.x, wa.x, acc[i]); acc[i] = fmaf(ha.y, wa.y, acc[i]);
        acc[i] = fmaf(ha.z, wa.z, acc[i]); acc[i] = fmaf(ha.w, wa.w, acc[i]);
        acc[i] = fmaf(hb.x, wb.x, acc[i]); acc[i] = fmaf(hb.y, wb.y, acc[i]);
        acc[i] = fmaf(hb.z, wb.z, acc[i]); acc[i] = fmaf(hb.w, wb.w, acc[i]);
      }
    }
    #pragma unroll
    for (int i = 0; i < 6; ++i) acc[i] += __shfl_xor(acc[i], 32, 64);
    if (n_kh == 0) {
      #pragma unroll
      for (int i = 0; i < 6; ++i) {
        int j = jbe + i;
        if (j < DD) nbuf[n_n*NBS + j] = acc[i] + statl[boff + j];
      }
    }
    __syncthreads();
  };

  // ---------------- layer loop ----------------
  #pragma unroll 1
  for (int L = 0; L < NLAYERS; ++L) {
    const int s = (L == 0) ? 0 : 1;
    float* lslot = slot + L * SPL;

    if (tid < DD) {
      statl[BAO + tid] = p.Ab[s][tid];
      statl[BBO + tid] = p.Bb[s][tid];
      statl[SBO + tid] = p.Cb[s][tid] + p.Db[s][tid] + p.Eb[s][tid];
    }
    node_phase(p.Aw[s], Ax, BAO);
    node_phase(p.Bw[s], Bx, BBO);
    node_phase(p.Dw[s], Dx, ZBO);
    node_phase(p.Ew[s], Ex, ZBO);

    stage_wt(slab, p.Cw[s], tid);
    __syncthreads();

    // ---- edge GEMM: acc[r][i] = sum_k eold[e0+r][k] * Cw[k][jbe+i]
    float acc[4][6];
    #pragma unroll
    for (int r = 0; r < 4; ++r)
      #pragma unroll
      for (int i = 0; i < 6; ++i) acc[r][i] = 0.f;

    #pragma unroll 2
    for (int c = 0; c < 18; ++c) {
      const int k0 = c*4;
      float4 ev0 = *(const float4*)(eT + EIX(k0+0, e0));
      float4 ev1 = *(const float4*)(eT + EIX(k0+1, e0));
      float4 ev2 = *(const float4*)(eT + EIX(k0+2, e0));
      float4 ev3 = *(const float4*)(eT + EIX(k0+3, e0));
      #pragma unroll
      for (int i = 0; i < 6; ++i) {
        float4 w4 = *(const float4*)(slab + (jbe + i)*SLS + k0);
        acc[0][i] = fmaf(ev0.x, w4.x, acc[0][i]); acc[1][i] = fmaf(ev0.y, w4.x, acc[1][i]);
        acc[2][i] = fmaf(ev0.z, w4.x, acc[2][i]); acc[3][i] = fmaf(ev0.w, w4.x, acc[3][i]);
        acc[0][i] = fmaf(ev1.x, w4.y, acc[0][i]); acc[1][i] = fmaf(ev1.y, w4.y, acc[1][i]);
        acc[2][i] = fmaf(ev1.z, w4.y, acc[2][i]); acc[3][i] = fmaf(ev1.w, w4.y, acc[3][i]);
        acc[0][i] = fmaf(ev2.x, w4.z, acc[0][i]); acc[1][i] = fmaf(ev2.y, w4.z, acc[1][i]);
        acc[2][i] = fmaf(ev2.z, w4.z, acc[2][i]); acc[3][i] = fmaf(ev2.w, w4.z, acc[3][i]);
        acc[0][i] = fmaf(ev3.x, w4.w, acc[0][i]); acc[1][i] = fmaf(ev3.y, w4.w, acc[1][i]);
        acc[2][i] = fmaf(ev3.z, w4.w, acc[2][i]); acc[3][i] = fmaf(ev3.w, w4.w, acc[3][i]);
      }
    }

    // += Dx[dst] + Ex[src] + (Cb+Db+Eb)
    {
      int dl0 = dstloc[e0],   sl0 = srcloc[e0];
      int dl1 = dstloc[e0+1], sl1 = srcloc[e0+1];
      int dl2 = dstloc[e0+2], sl2 = srcloc[e0+2];
      int dl3 = dstloc[e0+3], sl3 = srcloc[e0+3];
      #pragma unroll
      for (int i = 0; i < 6; ++i) {
        int j = jbe + i;
        if (j < DD) {
          float bb = statl[SBO + j];
          acc[0][i] += Dx[dl0*NBS + j] + Ex[sl0*NBS + j] + bb;
          acc[1][i] += Dx[dl1*NBS + j] + Ex[sl1*NBS + j] + bb;
          acc[2][i] += Dx[dl2*NBS + j] + Ex[sl2*NBS + j] + bb;
          acc[3][i] += Dx[dl3*NBS + j] + Ex[sl3*NBS + j] + bb;
        }
      }
    }

    // e-stats from registers (wave = one col group, 64 lanes x 4 edges = all 256)
    #pragma unroll
    for (int i = 0; i < 6; ++i) {
      int j = jbe + i;
      float ps = (acc[0][i] + acc[1][i]) + (acc[2][i] + acc[3][i]);
      float qs = acc[0][i]*acc[0][i];
      qs = fmaf(acc[1][i], acc[1][i], qs);
      qs = fmaf(acc[2][i], acc[2][i], qs);
      qs = fmaf(acc[3][i], acc[3][i], qs);
      #pragma unroll
      for (int d = 1; d < 64; d <<= 1) {
        ps += __shfl_xor(ps, d, 64);
        qs += __shfl_xor(qs, d, 64);
      }
      if (lane == 0 && j < DD) {
        atomicAdd(lslot + 140 + j, ps);
        atomicAdd(lslot + 210 + j, qs);
      }
    }
    __syncthreads();   // all slab/Dx/Ex/eT reads complete

    // sigma -> fp16 side buffer (overlays Dx/Ex/slab). One b64 per col.
    #pragma unroll
    for (int i = 0; i < 6; ++i) {
      int j = jbe + i;
      if (j < DD) {
        float s0 = 1.f / (1.f + __expf(-acc[0][i]));
        float s1 = 1.f / (1.f + __expf(-acc[1][i]));
        float s2 = 1.f / (1.f + __expf(-acc[2][i]));
        float s3 = 1.f / (1.f + __expf(-acc[3][i]));
        __half2 h01 = __floats2half2_rn(s0, s1);
        __half2 h23 = __floats2half2_rn(s2, s3);
        uint2 pk;
        pk.x = *reinterpret_cast<unsigned*>(&h01);
        pk.y = *reinterpret_cast<unsigned*>(&h23);
        // dword col for edges (e0,e0+1) is 2*lane (even) -> aligned uint2
        *reinterpret_cast<uint2*>(sigb + SIX(j, 2*lane)) = pk;
      }
    }
    __syncthreads();

    // gather: x_new = Ax + num/den (RMW into Ax). 576 items = 32 n x 18 jq.
    if (tid < 576) {
      int n = tid / 18, jq = tid % 18;
      int j0 = jq * 4;
      bool v2 = (j0 + 2) < DD, v3 = (j0 + 3) < DD;
      float nm0 = 0.f, nm1 = 0.f, nm2 = 0.f, nm3 = 0.f;
      float dn0 = 0.f, dn1 = 0.f, dn2 = 0.f, dn3 = 0.f;
      int pb = ioff[n], pe = ioff[n + 1];
      for (int pp = pb; pp < pe; ++pp) {
        unsigned v = eidxS[pp];
        int e2 = v & 255, sl2 = v >> 8;
        int cb = e2 >> 1, h2 = e2 & 1;
        float s0 = __half2float(sigh[(SIX(j0+0, cb) << 1) + h2]);
        float s1 = __half2float(sigh[(SIX(j0+1, cb) << 1) + h2]);
        float s2 = v2 ? __half2float(sigh[(SIX(j0+2, cb) << 1) + h2]) : 0.f;
        float s3 = v3 ? __half2float(sigh[(SIX(j0+3, cb) << 1) + h2]) : 0.f;
        float4 b4 = *(const float4*)(Bx + sl2*NBS + j0);
        nm0 = fmaf(s0, b4.x, nm0); nm1 = fmaf(s1, b4.y, nm1);
        nm2 = fmaf(s2, b4.z, nm2); nm3 = fmaf(s3, b4.w, nm3);
        dn0 += s0; dn1 += s1; dn2 += s2; dn3 += s3;
      }
      float* axp = Ax + n*NBS + j0;
      float4 ax = *(const float4*)axp;
      ax.x += nm0 / (dn0 + EPS_AGG);
      ax.y += nm1 / (dn1 + EPS_AGG);
      ax.z += nm2 / (dn2 + EPS_AGG);
      ax.w += nm3 / (dn3 + EPS_AGG);
      *(float4*)axp = ax;
    }
    __syncthreads();

    // x-stats (280 threads: 70 cols x 4 node-quarters)
    if (tid < SPL) {
      int col = tid % DD, q = tid / DD;
      float sm = 0.f, sq = 0.f;
      #pragma unroll
      for (int r = 0; r < 8; ++r) {
        float v = Ax[(q*8 + r)*NBS + col];
        sm += v; sq = fmaf(v, v, sq);
      }
      atomicAdd(lslot + col, sm);
      atomicAdd(lslot + 70 + col, sq);
    }

    grid_sync(p.bar);

    // BN scale/shift from 8 slots
    if (tid < DD) {
      float sm = 0.f, sq = 0.f;
      #pragma unroll
      for (int sl2 = 0; sl2 < NSLOT; ++sl2) {
        const float* st = p.stats + (sl2*NLAYERS + L)*SPL;
        sm += __hip_atomic_load(st + tid,      __ATOMIC_RELAXED, __HIP_MEMORY_SCOPE_AGENT);
        sq += __hip_atomic_load(st + 70 + tid, __ATOMIC_RELAXED, __HIP_MEMORY_SCOPE_AGENT);
      }
      float mean = sm * (1.f/8192.f);
      float var  = sq * (1.f/8192.f) - mean*mean;
      float sc = p.gx[s][tid] * rsqrtf(var + EPS_BN);
      statl[SCX + tid] = sc;
      statl[SHX + tid] = fmaf(-mean, sc, p.bx[s][tid]);
    } else if (tid < 140) {
      int j = tid - DD;
      float sm = 0.f, sq = 0.f;
      #pragma unroll
      for (int sl2 = 0; sl2 < NSLOT; ++sl2) {
        const float* st = p.stats + (sl2*NLAYERS + L)*SPL;
        sm += __hip_atomic_load(st + 140 + j, __ATOMIC_RELAXED, __HIP_MEMORY_SCOPE_AGENT);
        sq += __hip_atomic_load(st + 210 + j, __ATOMIC_RELAXED, __HIP_MEMORY_SCOPE_AGENT);
      }
      float mean = sm * (1.f/65536.f);
      float var  = sq * (1.f/65536.f) - mean*mean;
      float sc = p.ge[s][j] * rsqrtf(var + EPS_BN);
      statl[SCE + j] = sc;
      statl[SHE + j] = fmaf(-mean, sc, p.gbe[s][j]);
    }
    __syncthreads();

    // apply BN+ReLU+residual: h (2304 = 3*768 exact)
    #pragma unroll
    for (int r = 0; r < 3; ++r) {
      int idx = tid + r*TPB;
      int n = idx / 72, j = idx - n*72;
      if (j < DD) {
        float xn = Ax[n*NBS + j];
        hN[n*NBS + j] += fmaxf(fmaf(xn, statl[SCX + j], statl[SHX + j]), 0.f);
      }
    }
    // apply BN+ReLU+residual: e — e_old re-read from eT (kept intact), b128
    #pragma unroll
    for (int i = 0; i < 6; ++i) {
      int j = jbe + i;
      if (j < DD) {
        float sc = statl[SCE + j], sh = statl[SHE + j];
        float* ep = eT + EIX(j, e0);
        float4 eo = *(const float4*)ep;
        eo.x += fmaxf(fmaf(acc[0][i], sc, sh), 0.f);
        eo.y += fmaxf(fmaf(acc[1][i], sc, sh), 0.f);
        eo.z += fmaxf(fmaf(acc[2][i], sc, sh), 0.f);
        eo.w += fmaxf(fmaf(acc[3][i], sc, sh), 0.f);
        *(float4*)ep = eo;
      }
    }
    __syncthreads();
  }

  // ---------------- readout ----------------
  if (tid < DD) {
    float mx = -3.4e38f, sm = 0.f;
    #pragma unroll 4
    for (int r = 0; r < 32; ++r) {
      float v = hN[r*NBS + tid];
      mx = fmaxf(mx, v); sm += v;
    }
    statl[tid]      = mx;               // gmp
    statl[70 + tid] = sm * (1.f/32.f);  // gap
  }
  __syncthreads();
  if (tid < 256) {
    float a = p.c1b[tid];
    for (int k = 0; k < DD; ++k) a = fmaf(statl[k],      p.c1w[k*256 + tid], a);
    for (int k = 0; k < DD; ++k) a = fmaf(statl[70 + k], p.c1w[(DD + k)*256 + tid], a);
    Ax[tid] = fmaxf(a, 0.f);
  }
  __syncthreads();
  if (tid == 0) {
    float sm = 0.f, sq = 0.f;
    for (int k = 0; k < 256; ++k) { float v = Ax[k]; sm += v; sq = fmaf(v, v, sq); }
    float mean = sm * (1.f/256.f);
    float var  = sq * (1.f/256.f) - mean*mean;
    statl[560] = mean;
    statl[561] = rsqrtf(var + EPS_LN);
  }
  __syncthreads();
  if (tid < 256) {
    float v = (Ax[tid] - statl[560]) * statl[561];
    Bx[tid] = fmaf(v, p.lng[tid], p.lnb[tid]);
  }
  __syncthreads();
  if (tid < 10) {
    float a = p.c2b[tid];
    for (int k = 0; k < 256; ++k) a = fmaf(Bx[k], p.c2w[k*10 + tid], a);
    p.out[g*10 + tid] = a;
  }
}

extern "C" void kernel_launch(void* const* d_in, const int* in_sizes, int n_in,
                              void* d_out, int out_size, void* d_ws, size_t ws_size,
                              hipStream_t stream) {
  (void)in_sizes; (void)n_in; (void)out_size; (void)ws_size;
  GPSParams p;
  p.x   = (const float*)d_in[0];
  p.ei  = (const int*)  d_in[1];
  p.ea  = (const float*)d_in[2];
  p.wn  = (const float*)d_in[4];  p.bnn = (const float*)d_in[5];
  p.we  = (const float*)d_in[6];  p.web = (const float*)d_in[7];
  int i = 8;
  for (int s = 0; s < 2; ++s) {
    p.Aw[s] = (const float*)d_in[i++]; p.Ab[s] = (const float*)d_in[i++];
    p.Bw[s] = (const float*)d_in[i++]; p.Bb[s] = (const float*)d_in[i++];
    p.Cw[s] = (const float*)d_in[i++]; p.Cb[s] = (const float*)d_in[i++];
    p.Dw[s] = (const float*)d_in[i++]; p.Db[s] = (const float*)d_in[i++];
    p.Ew[s] = (const float*)d_in[i++]; p.Eb[s] = (const float*)d_in[i++];
    p.gx[s] = (const float*)d_in[i++]; p.bx[s] = (const float*)d_in[i++];
    p.ge[s] = (const float*)d_in[i++]; p.gbe[s] = (const float*)d_in[i++];
  }
  p.c1w = (const float*)d_in[36]; p.c1b = (const float*)d_in[37];
  p.lng = (const float*)d_in[38]; p.lnb = (const float*)d_in[39];
  p.c2w = (const float*)d_in[40]; p.c2b = (const float*)d_in[41];
  p.out = (float*)d_out;
  p.bar = (unsigned*)d_ws;
  p.stats = (float*)((char*)d_ws + 4096);

  hipMemsetAsync(d_ws, 0, 4096 + NSLOT*NLAYERS*SPL*4, stream);

  hipFuncSetAttribute((const void*)gps_kernel,
                      hipFuncAttributeMaxDynamicSharedMemorySize, SMEM_BYTES);

  void* args[] = { (void*)&p };
  hipError_t err = hipLaunchCooperativeKernel((const void*)gps_kernel,
                                              dim3(NBLK), dim3(TPB),
                                              args, SMEM_BYTES, stream);
  if (err != hipSuccess) {
    gps_kernel<<<dim3(NBLK), dim3(TPB), SMEM_BYTES, stream>>>(p);
  }
}